// Round 5
// baseline (2929.742 us; speedup 1.0000x reference)
//
#include <hip/hip_runtime.h>
#include <stdint.h>

typedef unsigned short u16;

#define HW   96
#define NPIX (HW*HW)      // 9216
#define BBATCH 2
#define NVIEW  5
#define NIMG 10

// ---------- scalar converters ----------
__device__ __forceinline__ float bf2f(u16 u) {
    union { unsigned int i; float f; } v; v.i = ((unsigned int)u) << 16; return v.f;
}
__device__ __forceinline__ float h2f(u16 u) {
    union { u16 u; _Float16 h; } v; v.u = u; return (float)v.h;
}
__device__ __forceinline__ u16 f2h(float f) {
    union { u16 u; _Float16 h; } v; v.h = (_Float16)f; return v.u;
}
// dual-dtype scalar load: input buffer is f32 if isf32, else bf16
__device__ __forceinline__ float ldf(const void* p, size_t i, int isf32) {
    return isf32 ? ((const float*)p)[i] : bf2f(((const u16*)p)[i]);
}

// ---------- input dtype detection ----------
// If focal is f32, even-indexed u16s are low mantissa words (uniform bits) ->
// bf16 exponent >=160 occurs w.p. ~0.37 each. Genuine bf16 N(0,1) data never
// exceeds exponent ~134. One block.
__global__ __launch_bounds__(256)
void k_detect(const u16* __restrict__ focal, int* __restrict__ flag)
{
    const int tid = threadIdx.x;
    int bad = 0;
    for (int k = tid; k < 2048; k += 256) {
        const u16 u = focal[2 * k];
        const int e = (u >> 7) & 0xFF;
        if (e >= 160) bad = 1;
    }
    __shared__ int s[256];
    s[tid] = bad;
    __syncthreads();
    if (tid == 0) {
        int b = 0;
        #pragma unroll 8
        for (int i = 0; i < 256; ++i) b |= s[i];
        *flag = b;
    }
}

// ---------- weight prep: tap-major fp16 [t][Cin][Cout], collapse 3D kernels ----------
__global__ __launch_bounds__(256)
void k_prep_w(const void* __restrict__ W1, const void* __restrict__ W2,
              const void* __restrict__ R1, const void* __restrict__ R2, const void* __restrict__ R3,
              u16* __restrict__ w1a, u16* __restrict__ w1b, u16* __restrict__ w2t,
              float* __restrict__ s1t, float* __restrict__ s2t, float* __restrict__ r3t,
              const int* __restrict__ flag)
{
    const int f32m = *flag;
    int id = blockIdx.x * 256 + threadIdx.x;
    if (id < 589824) {                       // w1a/w1b: [(t*256+c)*256+o]
        int t = id >> 16; int r = id & 65535; int c = r >> 8; int o = r & 255;
        int kh = t / 3, kw = t % 3;
        w1a[id] = f2h(ldf(W1, ((size_t)(o * 512 + c) * 3 + kh) * 3 + kw, f32m));
        w1b[id] = f2h(ldf(W1, ((size_t)(o * 512 + 256 + c) * 3 + kh) * 3 + kw, f32m));
        return;
    }
    id -= 589824;
    if (id < 294912) {                       // w2t: [(t*256+c)*128+o]
        int t = id >> 15; int r = id & 32767; int c = r >> 7; int o = r & 127;
        w2t[id] = f2h(ldf(W2, ((size_t)(o * 256 + c) * 3 + t / 3) * 3 + (t % 3), f32m));
        return;
    }
    id -= 294912;
    if (id < 288) {                          // s1t[t*32+o] = sum_i R1[o,i,kd,kh,1]
        int t = id >> 5; int o = id & 31;
        float s = 0.f;
        for (int i = 0; i < 64; ++i)
            s += ldf(R1, ((size_t)((o * 64 + i) * 3 + t / 3) * 3 + t % 3) * 3 + 1, f32m);
        s1t[id] = s;
        return;
    }
    id -= 288;
    if (id < 4608) {                         // s2t[(t*32+i)*16+o] = R2[o,i,kd,kh,1]
        int o = id & 15; int r = id >> 4; int i = r & 31; int t = r >> 5;
        s2t[id] = ldf(R2, ((size_t)((o * 32 + i) * 3 + t / 3) * 3 + t % 3) * 3 + 1, f32m);
        return;
    }
    id -= 4608;
    if (id < 1024) {                         // r3t[i*64+o] = R3[o,i]
        int o = id & 63; int i = id >> 6;
        r3t[id] = ldf(R3, (size_t)o * 16 + i, f32m);
    }
}

// ---------- init cost_agg to b3 (ws is poisoned before every launch) ----------
__global__ __launch_bounds__(256)
void k_zero_ca(float* __restrict__ ca, const void* __restrict__ b3, const int* __restrict__ flag)
{
    const int id = blockIdx.x * 256 + threadIdx.x;
    if (id < BBATCH * NPIX) ca[id] = ldf(b3, 0, *flag);
}

// ---------- 3x3 conv, implicit GEMM, fp32 accumulation, fp16 output ----------
// LAYOUT 0: input NCHW (f32 or bf16 per flag); LAYOUT 1: input NHWC fp16 (ws)
// wt: fp16 [9][Cin][Cout]; add: optional fp16 NHWC (ws); bias: original dtype
template<int LAYOUT>
__global__ __launch_bounds__(256)
void k_conv3x3(const void* __restrict__ in, const u16* __restrict__ wt,
               const u16* __restrict__ add, const void* __restrict__ bias,
               u16* __restrict__ outp, const int* __restrict__ flag,
               int Cin, int Cout, int imgBase, int imgMul, int addDiv, int relu)
{
    const int f32m = *flag;
    const int nOT = Cout >> 6;
    int b = blockIdx.x;
    const int ot = b % nOT; b /= nOT;
    const int h = b % HW; const int img = b / HW;
    const int gimg = imgBase + img * imgMul;
    const int o0 = ot * 64;
    const int tid = threadIdx.x;
    const int tx = tid & 15, ty = tid >> 4;

    __shared__ float As[32][100];            // halo'd row tile [c][w+1]
    __shared__ float Bs[3][32][68];          // 3 dw-taps co-staged

    float acc[6][4] = {};

    const size_t imgOff = (size_t)gimg * NPIX * Cin;

    for (int dh = -1; dh <= 1; ++dh) {
        const int hh = h + dh;
        if ((unsigned)hh >= (unsigned)HW) continue;   // block-uniform
        for (int c0 = 0; c0 < Cin; c0 += 32) {
            __syncthreads();
            if (LAYOUT == 0) {
                // NCHW: 32 ch-rows x 96 w, halo edges zeroed
                #pragma unroll
                for (int k = 0; k < 3; ++k) {
                    int g = tid + k * 256;           // 0..767
                    int c = g / 24, q = g % 24;
                    const size_t eoff = imgOff + (size_t)(c0 + c) * NPIX + (size_t)hh * HW + q * 4;
                    float f0, f1, f2, f3;
                    if (f32m) {
                        const float4 v = *(const float4*)((const float*)in + eoff);
                        f0 = v.x; f1 = v.y; f2 = v.z; f3 = v.w;
                    } else {
                        const ushort4 v = *(const ushort4*)((const u16*)in + eoff);
                        f0 = bf2f(v.x); f1 = bf2f(v.y); f2 = bf2f(v.z); f3 = bf2f(v.w);
                    }
                    As[c][1 + q * 4 + 0] = f0;
                    As[c][1 + q * 4 + 1] = f1;
                    As[c][1 + q * 4 + 2] = f2;
                    As[c][1 + q * 4 + 3] = f3;
                    if (q == 0)  As[c][0]  = 0.f;
                    if (q == 23) As[c][97] = 0.f;
                }
            } else {
                // NHWC fp16: 98 halo px x 32 ch
                const u16* rbase = (const u16*)in + imgOff + (size_t)hh * HW * Cin;
                #pragma unroll
                for (int k = 0; k < 4; ++k) {
                    int g = tid + k * 256;
                    if (g < 784) {
                        int p = g >> 3, cu = g & 7;  // p in 0..97, w = p-1
                        int w = p - 1;
                        float f0 = 0.f, f1 = 0.f, f2 = 0.f, f3 = 0.f;
                        if ((unsigned)w < (unsigned)HW) {
                            const ushort4 v = *(const ushort4*)(rbase + (size_t)w * Cin + c0 + cu * 4);
                            f0 = h2f(v.x); f1 = h2f(v.y); f2 = h2f(v.z); f3 = h2f(v.w);
                        }
                        const int c = cu * 4;
                        As[c + 0][p] = f0; As[c + 1][p] = f1;
                        As[c + 2][p] = f2; As[c + 3][p] = f3;
                    }
                }
            }
            // B tiles: 3 taps x 32 ch x 64 outs (fp16 weights)
            #pragma unroll
            for (int k = 0; k < 6; ++k) {
                int g = tid + k * 256;               // 0..1535
                int tap = g >> 9, c = (g >> 4) & 31, og = g & 15;
                const int t = (dh + 1) * 3 + tap;
                const ushort4 v = *(const ushort4*)(wt + ((size_t)t * Cin + c0 + c) * Cout + o0 + og * 4);
                Bs[tap][c][og * 4 + 0] = h2f(v.x); Bs[tap][c][og * 4 + 1] = h2f(v.y);
                Bs[tap][c][og * 4 + 2] = h2f(v.z); Bs[tap][c][og * 4 + 3] = h2f(v.w);
            }
            __syncthreads();
            #pragma unroll 4
            for (int c = 0; c < 32; ++c) {
                float av[8];
                #pragma unroll
                for (int i = 0; i < 8; ++i) av[i] = As[c][ty * 6 + i];   // covers dw -1..1
                #pragma unroll
                for (int dwi = 0; dwi < 3; ++dwi) {
                    const float bv0 = Bs[dwi][c][tx * 4 + 0], bv1 = Bs[dwi][c][tx * 4 + 1];
                    const float bv2 = Bs[dwi][c][tx * 4 + 2], bv3 = Bs[dwi][c][tx * 4 + 3];
                    #pragma unroll
                    for (int i = 0; i < 6; ++i) {
                        const float a = av[i + dwi];
                        acc[i][0] += a * bv0; acc[i][1] += a * bv1;
                        acc[i][2] += a * bv2; acc[i][3] += a * bv3;
                    }
                }
            }
        }
    }

    float bv[4] = {0.f, 0.f, 0.f, 0.f};
    if (bias) {
        #pragma unroll
        for (int j = 0; j < 4; ++j) bv[j] = ldf(bias, o0 + tx * 4 + j, f32m);
    }
    #pragma unroll
    for (int i = 0; i < 6; ++i) {
        const int p = ty * 6 + i;
        float v0 = acc[i][0] + bv[0], v1 = acc[i][1] + bv[1];
        float v2 = acc[i][2] + bv[2], v3 = acc[i][3] + bv[3];
        if (add) {
            const ushort4 a = *(const ushort4*)(add + ((size_t)(gimg / addDiv) * NPIX + (size_t)h * HW + p) * Cout + o0 + tx * 4);
            v0 += h2f(a.x); v1 += h2f(a.y); v2 += h2f(a.z); v3 += h2f(a.w);
        }
        if (relu) { v0 = fmaxf(v0, 0.f); v1 = fmaxf(v1, 0.f); v2 = fmaxf(v2, 0.f); v3 = fmaxf(v3, 0.f); }
        const size_t oidx = ((size_t)img * NPIX + (size_t)h * HW + p) * Cout + o0 + tx * 4;
        ushort4 w4; w4.x = f2h(v0); w4.y = f2h(v1); w4.z = f2h(v2); w4.w = f2h(v3);
        *(ushort4*)(outp + oidx) = w4;
    }
}

// ---------- 1x1 conv (128->1) on one image, accumulate mean into cost_agg ----------
__global__ __launch_bounds__(256)
void k_cost_acc(const u16* __restrict__ x2l, const void* __restrict__ W3,
                float* __restrict__ cab, const int* __restrict__ flag)
{
    const int f32m = *flag;
    const int wv = threadIdx.x >> 6, lane = threadIdx.x & 63;
    const int hw = blockIdx.x * 4 + wv;
    const int c = lane * 2;
    const ushort2 v = *(const ushort2*)(x2l + (size_t)hw * 128 + c);
    float s = ldf(W3, c, f32m) * h2f(v.x) + ldf(W3, c + 1, f32m) * h2f(v.y);
    #pragma unroll
    for (int off = 32; off; off >>= 1) s += __shfl_xor(s, off);
    if (lane == 0) cab[hw] += s * 0.2f;
}

// ---------- collapsed 3D stage 1: 1->32ch 3x3 ----------
__global__ __launch_bounds__(256)
void k_d1(const float* __restrict__ cost_agg, const float* __restrict__ s1t,
          const void* __restrict__ rb1, float* __restrict__ t1, const int* __restrict__ flag)
{
    const int id = blockIdx.x * 256 + threadIdx.x;   // [b][hw][o], o<32
    const int o = id & 31; const int r = id >> 5;
    const int hw = r % NPIX; const int bimg = r / NPIX;
    const int y = hw / HW, x = hw % HW;
    const float* ca = cost_agg + (size_t)bimg * NPIX;
    float s = ldf(rb1, o, *flag);
    #pragma unroll
    for (int t = 0; t < 9; ++t) {
        const int yy = y + t / 3 - 1, xx = x + t % 3 - 1;
        if ((unsigned)yy < HW && (unsigned)xx < HW)
            s += s1t[t * 32 + o] * ca[yy * HW + xx];
    }
    t1[id] = fmaxf(s, 0.f);
}

// ---------- collapsed 3D stage 2: 32->16ch 3x3 ----------
__global__ __launch_bounds__(256)
void k_d2(const float* __restrict__ t1, const float* __restrict__ s2t,
          const void* __restrict__ rb2, float* __restrict__ t2, const int* __restrict__ flag)
{
    const int id = blockIdx.x * 256 + threadIdx.x;   // [b][hw][o], o<16
    const int o = id & 15; const int r = id >> 4;
    const int hw = r % NPIX; const int bimg = r / NPIX;
    const int y = hw / HW, x = hw % HW;
    float s = ldf(rb2, o, *flag);
    for (int t = 0; t < 9; ++t) {
        const int yy = y + t / 3 - 1, xx = x + t % 3 - 1;
        if ((unsigned)yy < HW && (unsigned)xx < HW) {
            const float* tp = t1 + ((size_t)bimg * NPIX + yy * HW + xx) * 32;
            #pragma unroll
            for (int i = 0; i < 32; ++i)
                s += s2t[(t * 32 + i) * 16 + o] * tp[i];
        }
    }
    t2[id] = fmaxf(s, 0.f);
}

// ---------- 1x1 16->64 + softmax + both outputs (f32) ----------
__global__ __launch_bounds__(256)
void k_d3(const float* __restrict__ t2, const float* __restrict__ r3t,
          const void* __restrict__ rb3, float* __restrict__ out, const int* __restrict__ flag)
{
    const int f32m = *flag;
    const int wv = threadIdx.x >> 6, o = threadIdx.x & 63;
    const int pix = blockIdx.x * 4 + wv;     // [b][hw]
    const float* tp = t2 + (size_t)pix * 16;
    float cv = ldf(rb3, o, f32m);
    #pragma unroll
    for (int i = 0; i < 16; ++i) cv += r3t[i * 64 + o] * tp[i];
    const float z = -cv;
    float m = z;
    #pragma unroll
    for (int off = 32; off; off >>= 1) m = fmaxf(m, __shfl_xor(m, off));
    const float e = __expf(z - m);
    float s = e;
    #pragma unroll
    for (int off = 32; off; off >>= 1) s += __shfl_xor(s, off);
    const float p = e / s;
    const size_t idx = (size_t)pix * 64 + o;
    out[idx] = cv;                                       // cost_volume (B,H,W,64) f32
    out[idx + (size_t)BBATCH * NPIX * 64] = p;           // depth_probs (B,H,W,64) f32
}

extern "C" void kernel_launch(void* const* d_in, const int* in_sizes, int n_in,
                              void* d_out, int out_size, void* d_ws, size_t ws_size,
                              hipStream_t stream)
{
    (void)in_sizes; (void)n_in; (void)out_size; (void)ws_size;
    const void* focal = d_in[0];
    const void* W1  = d_in[3];
    const void* b1  = d_in[4];
    const void* W2  = d_in[5];
    const void* b2  = d_in[6];
    const void* W3  = d_in[7];
    const void* b3  = d_in[8];
    const void* R1  = d_in[9];
    const void* rb1 = d_in[10];
    const void* R2  = d_in[11];
    const void* rb2 = d_in[12];
    const void* R3  = d_in[13];
    const void* rb3 = d_in[14];

    // workspace layout — total 30,178,496 B (28.8 MiB)
    char* ws = (char*)d_ws;
    u16*   w1a  = (u16*)(ws + 0);             //  1,179,648
    u16*   w1b  = (u16*)(ws + 1179648);       //  1,179,648
    u16*   w2t  = (u16*)(ws + 2359296);       //    589,824
    float* s1t  = (float*)(ws + 2949120);     //      1,152
    float* s2t  = (float*)(ws + 2950272);     //     18,432
    float* r3t  = (float*)(ws + 2968704);     //      4,096
    int*   flag = (int*)(ws + 2972800);       //         64
    float* ca   = (float*)(ws + 2972864);     //     73,728  fp32 [2][9216]
    float* t1   = (float*)(ws + 3046592);     //  2,359,296
    float* t2   = (float*)(ws + 5405888);     //  1,179,648
    u16*   refp = (u16*)(ws + 6585536);       //  9,437,184  fp16 NHWC (2 imgs x 256)
    u16*   x1   = (u16*)(ws + 16022720);      //  9,437,184  fp16 NHWC (2 imgs x 256)
    u16*   x2   = (u16*)(ws + 25459904);      //  4,718,592  fp16 NHWC (2 imgs x 128)

    k_detect<<<1, 256, 0, stream>>>((const u16*)focal, flag);
    k_prep_w<<<(890656 + 255) / 256, 256, 0, stream>>>(W1, W2, R1, R2, R3, w1a, w1b, w2t, s1t, s2t, r3t, flag);
    k_zero_ca<<<(BBATCH * NPIX + 255) / 256, 256, 0, stream>>>(ca, b3, flag);

    // ref-channel half of conv1 on the n=0 image of each batch -> refp (fp16, 2 images)
    k_conv3x3<0><<<BBATCH * HW * 4, 256, 0, stream>>>(focal, w1b, nullptr, nullptr, refp, flag,
                                                      256, 256, /*imgBase*/0, /*imgMul*/NVIEW, 1, 0);

    // process images 2 at a time: conv1 -> x1, conv2 -> x2, accumulate cost
    for (int cb = 0; cb < NIMG; cb += 2) {
        k_conv3x3<0><<<2 * HW * 4, 256, 0, stream>>>(focal, w1a, refp, b1, x1, flag,
                                                     256, 256, /*imgBase*/cb, /*imgMul*/1, /*addDiv*/NVIEW, 1);
        k_conv3x3<1><<<2 * HW * 2, 256, 0, stream>>>(x1, w2t, nullptr, b2, x2, flag,
                                                     256, 128, /*imgBase*/0, /*imgMul*/1, 1, 1);
        for (int li = 0; li < 2; ++li) {
            const int gimg = cb + li;
            k_cost_acc<<<NPIX / 4, 256, 0, stream>>>(x2 + (size_t)li * NPIX * 128, W3,
                                                     ca + (size_t)(gimg / NVIEW) * NPIX, flag);
        }
    }

    k_d1<<<(BBATCH * NPIX * 32) / 256, 256, 0, stream>>>(ca, s1t, rb1, t1, flag);
    k_d2<<<(BBATCH * NPIX * 16) / 256, 256, 0, stream>>>(t1, s2t, rb2, t2, flag);
    k_d3<<<(BBATCH * NPIX) / 4, 256, 0, stream>>>(t2, r3t, rb3, (float*)d_out, flag);
}

// Round 6
// 554.353 us; speedup vs baseline: 5.2850x; 5.2850x over previous
//
#include <hip/hip_runtime.h>
#include <stdint.h>

typedef unsigned short u16;
typedef _Float16 f16;
typedef _Float16 f16x4 __attribute__((ext_vector_type(4)));
typedef _Float16 f16x8 __attribute__((ext_vector_type(8)));
typedef float    f32x4 __attribute__((ext_vector_type(4)));

#define HW   96
#define NPIX (HW*HW)      // 9216
#define BBATCH 2
#define NVIEW  5
#define NIMG 10

// LDS plan (bytes): A [98 px][36 f16] @0 (7056) ; B [3 tap][128 o][36 f16] @7056 (27648)
// epilogue reuses the same space (per-wave 6144B transpose tiles / 384B cost scratch)
#define LDS_B_OFF 7056
#define LDS_BYTES (7056 + 27648)

// ---------- weight prep: [tap][o][c] fp16; collapse 3D convs (W=1 dim => only kw=1 taps) ----------
__global__ __launch_bounds__(256)
void k_prep_w(const float* __restrict__ W1, const float* __restrict__ W2,
              const float* __restrict__ R1, const float* __restrict__ R2, const float* __restrict__ R3,
              u16* __restrict__ w1a, u16* __restrict__ w1b, u16* __restrict__ w2t,
              float* __restrict__ s1t, float* __restrict__ s2t, float* __restrict__ r3t)
{
    int id = blockIdx.x * 256 + threadIdx.x;
    if (id < 589824) {                       // w1a/w1b: [(t*256+o)*256+c]
        int t = id >> 16; int r = id & 65535; int o = r >> 8; int c = r & 255;
        int kh = t / 3, kw = t % 3;
        *(f16*)&w1a[id] = (f16)W1[((size_t)(o * 512 + c) * 3 + kh) * 3 + kw];
        *(f16*)&w1b[id] = (f16)W1[((size_t)(o * 512 + 256 + c) * 3 + kh) * 3 + kw];
        return;
    }
    id -= 589824;
    if (id < 294912) {                       // w2t: [(t*128+o)*256+c]
        int t = id >> 15; int r = id & 32767; int o = r >> 8; int c = r & 255;
        *(f16*)&w2t[id] = (f16)W2[((size_t)(o * 256 + c) * 3 + t / 3) * 3 + (t % 3)];
        return;
    }
    id -= 294912;
    if (id < 288) {                          // s1t[t*32+o] = sum_i R1[o,i,kd,kh,1]
        int t = id >> 5; int o = id & 31;
        float s = 0.f;
        for (int i = 0; i < 64; ++i)
            s += R1[((size_t)((o * 64 + i) * 3 + t / 3) * 3 + t % 3) * 3 + 1];
        s1t[id] = s;
        return;
    }
    id -= 288;
    if (id < 4608) {                         // s2t[(t*32+i)*16+o] = R2[o,i,kd,kh,1]
        int o = id & 15; int r = id >> 4; int i = r & 31; int t = r >> 5;
        s2t[id] = R2[((size_t)((o * 32 + i) * 3 + t / 3) * 3 + t % 3) * 3 + 1];
        return;
    }
    id -= 4608;
    if (id < 1024) {                         // r3t[i*64+o] = R3[o,i]
        int o = id & 63; int i = id >> 6;
        r3t[id] = R3[(size_t)o * 16 + i];
    }
}

// ---------- MFMA 3x3 conv ----------
// MODE 0: in=focal f32 NCHW (img = y*5), out = refp (blocked f16), no bias/relu
// MODE 1: in=focal f32 NCHW (img = ib+y), + refp + b1 + relu -> x1 (blocked f16, img y)
// MODE 2: in=x1 blocked f16 (img y), + b2 + relu, fused W3-dot -> pv[ib+y][hw] (f32)
// block = 128 thr = 2 waves; wave tile 96px x 64o; Cout covered = 128 (blockIdx.z picks half)
template<int MODE>
__global__ __launch_bounds__(128)
void k_conv(const void* __restrict__ in, const u16* __restrict__ wt,
            const u16* __restrict__ refp, const float* __restrict__ bias,
            const float* __restrict__ W3, void* __restrict__ outp, int ib)
{
    constexpr int Cout = (MODE == 2) ? 128 : 256;
    const int h  = blockIdx.x;
    const int y  = blockIdx.y;
    const int ob = blockIdx.z * 128;
    const int gimg = (MODE == 0) ? y * NVIEW : ib + y;
    const int tid = threadIdx.x;
    const int wv = tid >> 6, l = tid & 63;
    const int lane16 = l & 15, quad = l >> 4;

    __shared__ __align__(16) char lds[LDS_BYTES];

    f32x4 acc[6][4];
    #pragma unroll
    for (int mf = 0; mf < 6; ++mf)
        #pragma unroll
        for (int nf = 0; nf < 4; ++nf) acc[mf][nf] = (f32x4){0.f, 0.f, 0.f, 0.f};

    // halo columns (px index 0 and 97): zero once (only c<32 bytes are ever read)
    if (tid < 32) {
        const int row = (tid >> 4) ? 97 : 0;
        ((unsigned int*)(lds + row * 72))[tid & 15] = 0u;
    }

    for (int dh = -1; dh <= 1; ++dh) {
        const int hh = h + dh;
        if ((unsigned)hh >= (unsigned)HW) continue;
        for (int c0 = 0; c0 < 256; c0 += 32) {
            __syncthreads();
            // ---- stage A: [px+1][c] f16, row stride 72 B ----
            if (MODE != 2) {
                const int c = tid >> 2, pxb = (tid & 3) * 24;
                const float* src = (const float*)in +
                    ((size_t)(gimg * 256 + c0 + c)) * NPIX + (size_t)hh * HW + pxb;
                #pragma unroll
                for (int i = 0; i < 6; ++i) {
                    const float4 v = ((const float4*)src)[i];
                    const int px = pxb + i * 4;
                    *(f16*)(lds + (px + 1) * 72 + c * 2) = (f16)v.x;
                    *(f16*)(lds + (px + 2) * 72 + c * 2) = (f16)v.y;
                    *(f16*)(lds + (px + 3) * 72 + c * 2) = (f16)v.z;
                    *(f16*)(lds + (px + 4) * 72 + c * 2) = (f16)v.w;
                }
            } else if (tid < 96) {
                const int px = tid;
                const uint4* g = (const uint4*)((const u16*)in +
                    ((((size_t)y * HW + hh) * 8 + (c0 >> 5)) * HW + px) * 32);
                char* arow = lds + (px + 1) * 72;
                #pragma unroll
                for (int p = 0; p < 4; ++p) {
                    const uint4 v = g[p];
                    ((uint2*)(arow + p * 16))[0] = make_uint2(v.x, v.y);
                    ((uint2*)(arow + p * 16))[1] = make_uint2(v.z, v.w);
                }
            }
            // ---- stage B: 3 taps x 128 o x 32 c ----
            {
                const int o = tid & 127;
                #pragma unroll
                for (int dwt = 0; dwt < 3; ++dwt) {
                    const int tap = (dh + 1) * 3 + dwt;
                    const uint4* g = (const uint4*)(wt + ((size_t)tap * Cout + ob + o) * 256 + c0);
                    char* brow = lds + LDS_B_OFF + (dwt * 128 + o) * 72;
                    #pragma unroll
                    for (int p = 0; p < 4; ++p) {
                        const uint4 v = g[p];
                        ((uint2*)(brow + p * 16))[0] = make_uint2(v.x, v.y);
                        ((uint2*)(brow + p * 16))[1] = make_uint2(v.z, v.w);
                    }
                }
            }
            __syncthreads();
            // ---- compute: per dw, 6 a-frags + 4 b-frags -> 24 MFMAs ----
            #pragma unroll
            for (int dw = 0; dw < 3; ++dw) {
                f16x8 af[6];
                #pragma unroll
                for (int mf = 0; mf < 6; ++mf) {
                    const char* pa = lds + (mf * 16 + lane16 + dw) * 72 + quad * 16;
                    const f16x4 lo = *(const f16x4*)pa;
                    const f16x4 hi = *(const f16x4*)(pa + 8);
                    af[mf] = __builtin_shufflevector(lo, hi, 0, 1, 2, 3, 4, 5, 6, 7);
                }
                #pragma unroll
                for (int nf = 0; nf < 4; ++nf) {
                    const char* pb = lds + LDS_B_OFF +
                        (dw * 128 + wv * 64 + nf * 16 + lane16) * 72 + quad * 16;
                    const f16x4 lo = *(const f16x4*)pb;
                    const f16x4 hi = *(const f16x4*)(pb + 8);
                    const f16x8 bf = __builtin_shufflevector(lo, hi, 0, 1, 2, 3, 4, 5, 6, 7);
                    #pragma unroll
                    for (int mf = 0; mf < 6; ++mf)
                        acc[mf][nf] = __builtin_amdgcn_mfma_f32_16x16x32_f16(af[mf], bf, acc[mf][nf], 0, 0, 0);
                }
            }
        }
    }

    if (MODE <= 1) {
        // ---- LDS-transpose epilogue -> blocked f16 [img][row][cblk][px][32] ----
        float bias4[4] = {0.f, 0.f, 0.f, 0.f};
        if (MODE == 1) {
            #pragma unroll
            for (int nf = 0; nf < 4; ++nf) bias4[nf] = bias[ob + wv * 64 + nf * 16 + lane16];
        }
        char* epi = lds + wv * 6144;
        u16* outg = (u16*)outp;
        #pragma unroll
        for (int p = 0; p < 2; ++p) {
            __syncthreads();
            #pragma unroll
            for (int nn = 0; nn < 2; ++nn) {
                const int nf = p * 2 + nn;
                #pragma unroll
                for (int mf = 0; mf < 6; ++mf)
                    #pragma unroll
                    for (int r = 0; r < 4; ++r) {
                        const int px = mf * 16 + quad * 4 + r;
                        *(f16*)(epi + px * 64 + (nn * 16 + lane16) * 2) =
                            (f16)(acc[mf][nf][r] + bias4[nf]);
                    }
            }
            __syncthreads();
            const int cblk = ((ob + wv * 64) >> 5) + p;
            const size_t obase = (((size_t)y * HW + h) * 8 + cblk) * HW * 32;
            const size_t rbase = (((size_t)(gimg / NVIEW) * HW + h) * 8 + cblk) * HW * 32;
            #pragma unroll
            for (int i = 0; i < 6; ++i) {
                const int cid = l * 6 + i;
                const int px = cid >> 2, part = cid & 3;
                f16x8 v = *(const f16x8*)(epi + px * 64 + part * 16);
                if (MODE == 1) {
                    const f16x8 rv = *(const f16x8*)((const u16*)refp + rbase + (size_t)px * 32 + part * 8);
                    #pragma unroll
                    for (int j = 0; j < 8; ++j)
                        v[j] = (f16)fmaxf((float)v[j] + (float)rv[j], 0.f);
                }
                *(f16x8*)(outg + obase + (size_t)px * 32 + part * 8) = v;
            }
        }
    } else {
        // ---- fused cost epilogue: pv[img][hw] = sum_o W3[o]*relu(acc+b2[o]) ----
        float w3v[4], b2v[4];
        #pragma unroll
        for (int nf = 0; nf < 4; ++nf) {
            const int o = wv * 64 + nf * 16 + lane16;
            w3v[nf] = W3[o]; b2v[nf] = bias[o];
        }
        float s[6][4];
        #pragma unroll
        for (int mf = 0; mf < 6; ++mf)
            #pragma unroll
            for (int r = 0; r < 4; ++r) {
                float t = 0.f;
                #pragma unroll
                for (int nf = 0; nf < 4; ++nf)
                    t += w3v[nf] * fmaxf(acc[mf][nf][r] + b2v[nf], 0.f);
                s[mf][r] = t;
            }
        #pragma unroll
        for (int xb = 1; xb < 16; xb <<= 1)
            #pragma unroll
            for (int mf = 0; mf < 6; ++mf)
                #pragma unroll
                for (int r = 0; r < 4; ++r)
                    s[mf][r] += __shfl_xor(s[mf][r], xb);
        __syncthreads();
        float* cs = (float*)lds;
        if (wv == 0 && lane16 == 0) {
            #pragma unroll
            for (int mf = 0; mf < 6; ++mf)
                #pragma unroll
                for (int r = 0; r < 4; ++r)
                    cs[mf * 16 + quad * 4 + r] = s[mf][r];
        }
        __syncthreads();
        if (wv == 1 && lane16 == 0) {
            float* pvp = (float*)outp + (size_t)gimg * NPIX + (size_t)h * HW;
            #pragma unroll
            for (int mf = 0; mf < 6; ++mf)
                #pragma unroll
                for (int r = 0; r < 4; ++r) {
                    const int px = mf * 16 + quad * 4 + r;
                    pvp[px] = cs[px] + s[mf][r];
                }
        }
    }
}

// ---------- mean over 5 views + b3 ----------
__global__ __launch_bounds__(256)
void k_cost_sum(const float* __restrict__ pv, const float* __restrict__ b3, float* __restrict__ ca)
{
    const int id = blockIdx.x * 256 + threadIdx.x;
    if (id >= BBATCH * NPIX) return;
    const int b = id / NPIX, hw = id % NPIX;
    float s = 0.f;
    #pragma unroll
    for (int n = 0; n < NVIEW; ++n) s += pv[(size_t)(b * NVIEW + n) * NPIX + hw];
    ca[id] = b3[0] + 0.2f * s;
}

// ---------- collapsed 3D stage 1: 1->32ch 3x3 ----------
__global__ __launch_bounds__(256)
void k_d1(const float* __restrict__ cost_agg, const float* __restrict__ s1t,
          const float* __restrict__ rb1, float* __restrict__ t1)
{
    const int id = blockIdx.x * 256 + threadIdx.x;   // [b][hw][o], o<32
    const int o = id & 31; const int r = id >> 5;
    const int hw = r % NPIX; const int bimg = r / NPIX;
    const int y = hw / HW, x = hw % HW;
    const float* ca = cost_agg + (size_t)bimg * NPIX;
    float s = rb1[o];
    #pragma unroll
    for (int t = 0; t < 9; ++t) {
        const int yy = y + t / 3 - 1, xx = x + t % 3 - 1;
        if ((unsigned)yy < HW && (unsigned)xx < HW)
            s += s1t[t * 32 + o] * ca[yy * HW + xx];
    }
    t1[id] = fmaxf(s, 0.f);
}

// ---------- collapsed 3D stage 2: 32->16ch 3x3 ----------
__global__ __launch_bounds__(256)
void k_d2(const float* __restrict__ t1, const float* __restrict__ s2t,
          const float* __restrict__ rb2, float* __restrict__ t2)
{
    const int id = blockIdx.x * 256 + threadIdx.x;   // [b][hw][o], o<16
    const int o = id & 15; const int r = id >> 4;
    const int hw = r % NPIX; const int bimg = r / NPIX;
    const int y = hw / HW, x = hw % HW;
    float s = rb2[o];
    for (int t = 0; t < 9; ++t) {
        const int yy = y + t / 3 - 1, xx = x + t % 3 - 1;
        if ((unsigned)yy < HW && (unsigned)xx < HW) {
            const float* tp = t1 + ((size_t)bimg * NPIX + yy * HW + xx) * 32;
            #pragma unroll
            for (int i = 0; i < 32; ++i)
                s += s2t[(t * 32 + i) * 16 + o] * tp[i];
        }
    }
    t2[id] = fmaxf(s, 0.f);
}

// ---------- 1x1 16->64 + softmax + both outputs (f32) ----------
__global__ __launch_bounds__(256)
void k_d3(const float* __restrict__ t2, const float* __restrict__ r3t,
          const float* __restrict__ rb3, float* __restrict__ out)
{
    const int wv = threadIdx.x >> 6, o = threadIdx.x & 63;
    const int pix = blockIdx.x * 4 + wv;     // [b][hw]
    const float* tp = t2 + (size_t)pix * 16;
    float cv = rb3[o];
    #pragma unroll
    for (int i = 0; i < 16; ++i) cv += r3t[i * 64 + o] * tp[i];
    const float z = -cv;
    float m = z;
    #pragma unroll
    for (int off = 32; off; off >>= 1) m = fmaxf(m, __shfl_xor(m, off));
    const float e = __expf(z - m);
    float s = e;
    #pragma unroll
    for (int off = 32; off; off >>= 1) s += __shfl_xor(s, off);
    const float p = e / s;
    const size_t idx = (size_t)pix * 64 + o;
    out[idx] = cv;
    out[idx + (size_t)BBATCH * NPIX * 64] = p;
}

extern "C" void kernel_launch(void* const* d_in, const int* in_sizes, int n_in,
                              void* d_out, int out_size, void* d_ws, size_t ws_size,
                              hipStream_t stream)
{
    (void)in_sizes; (void)n_in; (void)out_size;
    const float* focal = (const float*)d_in[0];
    const float* W1  = (const float*)d_in[3];
    const float* b1  = (const float*)d_in[4];
    const float* W2  = (const float*)d_in[5];
    const float* b2  = (const float*)d_in[6];
    const float* W3  = (const float*)d_in[7];
    const float* b3  = (const float*)d_in[8];
    const float* R1  = (const float*)d_in[9];
    const float* rb1 = (const float*)d_in[10];
    const float* R2  = (const float*)d_in[11];
    const float* rb2 = (const float*)d_in[12];
    const float* R3  = (const float*)d_in[13];
    const float* rb3 = (const float*)d_in[14];

    // workspace layout (256B-aligned slots)
    char* ws = (char*)d_ws;
    size_t off = 0;
    auto alloc = [&](size_t sz) { char* p = ws + off; off = (off + sz + 255) & ~(size_t)255; return p; };
    u16*   w1a  = (u16*)  alloc(1179648);
    u16*   w1b  = (u16*)  alloc(1179648);
    u16*   w2t  = (u16*)  alloc(589824);
    float* s1t  = (float*)alloc(1152);
    float* s2t  = (float*)alloc(18432);
    float* r3t  = (float*)alloc(4096);
    float* ca   = (float*)alloc(73728);
    float* t1   = (float*)alloc(2359296);
    float* t2   = (float*)alloc(1179648);
    float* pv   = (float*)alloc(NIMG * NPIX * 4);          // 368,640
    u16*   refp = (u16*)  alloc(2 * (size_t)HW * 8 * HW * 32 * 2);   // 9,437,184
    const size_t fixed = off;
    const size_t X1IMG = (size_t)HW * 8 * HW * 32 * 2;     // 4,718,592 B per image
    int C = 10;
    if (fixed + 10 * X1IMG > ws_size) C = 5;
    if (fixed + 5  * X1IMG > ws_size) C = 2;
    if (fixed + 2  * X1IMG > ws_size) C = 1;
    u16* x1 = (u16*)alloc(C * X1IMG);

    k_prep_w<<<(890656 + 255) / 256, 256, 0, stream>>>(W1, W2, R1, R2, R3, w1a, w1b, w2t, s1t, s2t, r3t);

    // ref half of conv1 on each batch's n=0 image -> refp (blocked f16)
    k_conv<0><<<dim3(HW, BBATCH, 2), 128, 0, stream>>>(focal, w1b, nullptr, nullptr, nullptr, refp, 0);

    for (int cb = 0; cb < NIMG; cb += C) {
        k_conv<1><<<dim3(HW, C, 2), 128, 0, stream>>>(focal, w1a, refp, b1, nullptr, x1, cb);
        k_conv<2><<<dim3(HW, C, 1), 128, 0, stream>>>(x1, w2t, nullptr, b2, W3, pv, cb);
    }

    k_cost_sum<<<(BBATCH * NPIX + 255) / 256, 256, 0, stream>>>(pv, b3, ca);
    k_d1<<<(BBATCH * NPIX * 32) / 256, 256, 0, stream>>>(ca, s1t, rb1, t1);
    k_d2<<<(BBATCH * NPIX * 16) / 256, 256, 0, stream>>>(t1, s2t, rb2, t2);
    k_d3<<<(BBATCH * NPIX) / 4, 256, 0, stream>>>(t2, r3t, rb3, (float*)d_out);
}

// Round 7
// 470.653 us; speedup vs baseline: 6.2248x; 1.1778x over previous
//
#include <hip/hip_runtime.h>
#include <stdint.h>

typedef unsigned short u16;
typedef _Float16 f16;
typedef _Float16 f16x8 __attribute__((ext_vector_type(8)));
typedef float    f32x4 __attribute__((ext_vector_type(4)));

#define HW   96
#define NPIX (HW*HW)      // 9216
#define BBATCH 2
#define NVIEW  5
#define NIMG 10

// LDS: A [98 rows][80 B] @0 (7840) ; B [3 dw][128 o][80 B] @7840 (30720) = 38560 B -> 4 blocks/CU
#define ASTR 80
#define LDS_B_OFF 7840
#define LDS_BYTES (7840 + 30720)

__device__ __forceinline__ u16 f16u(float f) {
    union { u16 u; f16 h; } v; v.h = (f16)f; return v.u;
}

// ---------- weight prep: [tap][o][c] fp16; collapse 3D convs (W=1 dim => only kw=1 taps) ----------
__global__ __launch_bounds__(256)
void k_prep_w(const float* __restrict__ W1, const float* __restrict__ W2,
              const float* __restrict__ R1, const float* __restrict__ R2, const float* __restrict__ R3,
              u16* __restrict__ w1a, u16* __restrict__ w1b, u16* __restrict__ w2t,
              float* __restrict__ s1t, float* __restrict__ s2t, float* __restrict__ r3t)
{
    int id = blockIdx.x * 256 + threadIdx.x;
    if (id < 589824) {                       // w1a/w1b: [(t*256+o)*256+c]
        int t = id >> 16; int r = id & 65535; int o = r >> 8; int c = r & 255;
        int kh = t / 3, kw = t % 3;
        *(f16*)&w1a[id] = (f16)W1[((size_t)(o * 512 + c) * 3 + kh) * 3 + kw];
        *(f16*)&w1b[id] = (f16)W1[((size_t)(o * 512 + 256 + c) * 3 + kh) * 3 + kw];
        return;
    }
    id -= 589824;
    if (id < 294912) {                       // w2t: [(t*128+o)*256+c]
        int t = id >> 15; int r = id & 32767; int o = r >> 8; int c = r & 255;
        *(f16*)&w2t[id] = (f16)W2[((size_t)(o * 256 + c) * 3 + t / 3) * 3 + (t % 3)];
        return;
    }
    id -= 294912;
    if (id < 288) {                          // s1t[t*32+o] = sum_i R1[o,i,kd,kh,1]
        int t = id >> 5; int o = id & 31;
        float s = 0.f;
        for (int i = 0; i < 64; ++i)
            s += R1[((size_t)((o * 64 + i) * 3 + t / 3) * 3 + t % 3) * 3 + 1];
        s1t[id] = s;
        return;
    }
    id -= 288;
    if (id < 4608) {                         // s2t[(t*32+i)*16+o] = R2[o,i,kd,kh,1]
        int o = id & 15; int r = id >> 4; int i = r & 31; int t = r >> 5;
        s2t[id] = R2[((size_t)((o * 32 + i) * 3 + t / 3) * 3 + t % 3) * 3 + 1];
        return;
    }
    id -= 4608;
    if (id < 1024) {                         // r3t[i*64+o] = R3[o,i]
        int o = id & 63; int i = id >> 6;
        r3t[id] = R3[(size_t)o * 16 + i];
    }
}

// ---------- NCHW f32 -> blocked f16 [img][row][cblk][px][32] ----------
__global__ __launch_bounds__(256)
void k_tr(const float* __restrict__ src, u16* __restrict__ dst, int img0, int imgMul)
{
    const int cblk = blockIdx.x, row = blockIdx.y, z = blockIdx.z;
    const int gimg = img0 + z * imgMul;
    const int tid = threadIdx.x;
    __shared__ u16 tile[96 * 40];            // [px][40], 80 B rows (16-aligned)
    const int c = tid >> 3, j = tid & 7;
    const float* s = src + ((size_t)(gimg * 256 + cblk * 32 + c)) * NPIX + (size_t)row * HW + j * 12;
    #pragma unroll
    for (int k = 0; k < 3; ++k) {
        const float4 v = ((const float4*)s)[k];
        const int px = j * 12 + k * 4;
        tile[(px + 0) * 40 + c] = f16u(v.x);
        tile[(px + 1) * 40 + c] = f16u(v.y);
        tile[(px + 2) * 40 + c] = f16u(v.z);
        tile[(px + 3) * 40 + c] = f16u(v.w);
    }
    __syncthreads();
    if (tid < 192) {
        const int px = tid >> 1, part = tid & 1;   // 32 B each
        const uint4 v0 = ((const uint4*)(tile + px * 40 + part * 16))[0];
        const uint4 v1 = ((const uint4*)(tile + px * 40 + part * 16))[1];
        uint4* d = (uint4*)(dst + ((((size_t)z * HW + row) * 8 + cblk) * HW + px) * 32 + part * 16);
        d[0] = v0; d[1] = v1;
    }
}

// ---------- MFMA 3x3 conv, blocked f16 input ----------
// MODE 0: in=feats2 (aimg=y=batch), out refp img y. no bias/relu.
// MODE 1: in=feats chunk (aimg=y), + refp[batch] + b1 + relu -> x1 img y.  gimg=ib+y.
// MODE 2: in=x1 (aimg=y), + b2 + relu, fused W3-dot -> pv[ib+y].
// 256 thr = 4 waves (wm px-half, wn o-half); block tile 96 px x 128 o; z picks o-half for Cout=256.
template<int MODE>
__global__ __launch_bounds__(256, 4)
void k_conv(const u16* __restrict__ in, const u16* __restrict__ wt,
            const u16* __restrict__ refp, const float* __restrict__ bias,
            const float* __restrict__ W3, void* __restrict__ outp, int ib)
{
    constexpr int Cout = (MODE == 2) ? 128 : 256;
    const int h  = blockIdx.x;
    const int y  = blockIdx.y;
    const int ob = blockIdx.z * 128;
    const int tid = threadIdx.x;
    const int wv = tid >> 6, l = tid & 63;
    const int wm = wv >> 1, wn = wv & 1;
    const int lane16 = l & 15, quad = l >> 4;

    __shared__ __align__(16) char lds[LDS_BYTES];

    f32x4 acc[3][4];
    #pragma unroll
    for (int mf = 0; mf < 3; ++mf)
        #pragma unroll
        for (int nf = 0; nf < 4; ++nf) acc[mf][nf] = (f32x4){0.f, 0.f, 0.f, 0.f};

    // zero halo rows 0 and 97 (first 64 B matter)
    if (tid < 32) {
        const int base = (tid >> 4) ? 97 * ASTR : 0;
        ((unsigned int*)(lds + base))[tid & 15] = 0u;
    }

    for (int dh = -1; dh <= 1; ++dh) {
        const int hh = h + dh;
        if ((unsigned)hh >= (unsigned)HW) continue;   // block-uniform
        for (int c0 = 0; c0 < 256; c0 += 32) {
            __syncthreads();
            // ---- stage A: 96 px x 32 c from blocked f16 ----
            if (tid < 192) {
                const int px = tid >> 1, half = tid & 1;
                const uint4* g = (const uint4*)(in +
                    ((((size_t)y * HW + hh) * 8 + (c0 >> 5)) * HW + px) * 32 + half * 16);
                const uint4 v0 = g[0], v1 = g[1];
                uint4* d = (uint4*)(lds + (px + 1) * ASTR + half * 32);
                d[0] = v0; d[1] = v1;
            }
            // ---- stage B: 3 dw-taps x 128 o x 32 c ----
            #pragma unroll
            for (int i = 0; i < 3; ++i) {
                const int idx = i * 256 + tid;       // 0..767
                const int dwt = idx >> 8, o = (idx >> 1) & 127, half = idx & 1;
                const int tap = (dh + 1) * 3 + dwt;
                const uint4* g = (const uint4*)(wt +
                    ((size_t)tap * Cout + ob + o) * 256 + c0 + half * 16);
                const uint4 v0 = g[0], v1 = g[1];
                uint4* d = (uint4*)(lds + LDS_B_OFF + (dwt * 128 + o) * ASTR + half * 32);
                d[0] = v0; d[1] = v1;
            }
            __syncthreads();
            // ---- compute: per dw, 3 A-frags + 4 B-frags -> 12 MFMAs ----
            #pragma unroll
            for (int dw = 0; dw < 3; ++dw) {
                f16x8 af[3];
                #pragma unroll
                for (int mf = 0; mf < 3; ++mf)
                    af[mf] = *(const f16x8*)(lds + (wm * 48 + mf * 16 + lane16 + dw) * ASTR + quad * 16);
                #pragma unroll
                for (int nf = 0; nf < 4; ++nf) {
                    const f16x8 bf = *(const f16x8*)(lds + LDS_B_OFF +
                        (dw * 128 + wn * 64 + nf * 16 + lane16) * ASTR + quad * 16);
                    #pragma unroll
                    for (int mf = 0; mf < 3; ++mf)
                        acc[mf][nf] = __builtin_amdgcn_mfma_f32_16x16x32_f16(af[mf], bf, acc[mf][nf], 0, 0, 0);
                }
            }
        }
    }

    if (MODE <= 1) {
        // ---- LDS-transpose epilogue -> blocked f16 [img][row][cblk][px][32] ----
        const int rimg = (MODE == 1) ? (ib + y) / NVIEW : 0;
        float bias4[4] = {0.f, 0.f, 0.f, 0.f};
        if (MODE == 1) {
            #pragma unroll
            for (int nf = 0; nf < 4; ++nf) bias4[nf] = bias[ob + wn * 64 + nf * 16 + lane16];
        }
        char* epi = lds + wv * 3072;                 // 48 px x 32 o f16 per wave
        u16* outg = (u16*)outp;
        #pragma unroll
        for (int p = 0; p < 2; ++p) {
            __syncthreads();
            #pragma unroll
            for (int nn = 0; nn < 2; ++nn) {
                const int nf = p * 2 + nn;
                #pragma unroll
                for (int mf = 0; mf < 3; ++mf)
                    #pragma unroll
                    for (int r = 0; r < 4; ++r) {
                        const int pxl = mf * 16 + quad * 4 + r;
                        *(u16*)(epi + pxl * 64 + (nn * 16 + lane16) * 2) =
                            f16u(acc[mf][nf][r] + bias4[nf]);
                    }
            }
            __syncthreads();
            const int cblk = (ob + wn * 64 + p * 32) >> 5;
            const size_t obase = (((size_t)y * HW + h) * 8 + cblk) * (size_t)(HW * 32);
            const size_t rbase = (((size_t)rimg * HW + h) * 8 + cblk) * (size_t)(HW * 32);
            #pragma unroll
            for (int i = 0; i < 3; ++i) {
                const int u = i * 64 + l;            // 0..191
                const int pxl = u >> 2, part = u & 3;
                f16x8 v = *(const f16x8*)(epi + pxl * 64 + part * 16);
                const int px = wm * 48 + pxl;
                if (MODE == 1) {
                    const f16x8 rv = *(const f16x8*)(refp + rbase + (size_t)px * 32 + part * 8);
                    #pragma unroll
                    for (int jj = 0; jj < 8; ++jj)
                        v[jj] = (f16)fmaxf((float)v[jj] + (float)rv[jj], 0.f);
                }
                *(f16x8*)(outg + obase + (size_t)px * 32 + part * 8) = v;
            }
        }
    } else {
        // ---- fused cost epilogue: pv[gimg][hw] = sum_o W3[o]*relu(acc+b2[o]) ----
        const int gimg = ib + y;
        float w3v[4], b2v[4];
        #pragma unroll
        for (int nf = 0; nf < 4; ++nf) {
            const int o = wn * 64 + nf * 16 + lane16;
            w3v[nf] = W3[o]; b2v[nf] = bias[o];
        }
        float s[3][4];
        #pragma unroll
        for (int mf = 0; mf < 3; ++mf)
            #pragma unroll
            for (int r = 0; r < 4; ++r) {
                float t = 0.f;
                #pragma unroll
                for (int nf = 0; nf < 4; ++nf)
                    t += w3v[nf] * fmaxf(acc[mf][nf][r] + b2v[nf], 0.f);
                s[mf][r] = t;
            }
        #pragma unroll
        for (int xb = 1; xb < 16; xb <<= 1)
            #pragma unroll
            for (int mf = 0; mf < 3; ++mf)
                #pragma unroll
                for (int r = 0; r < 4; ++r)
                    s[mf][r] += __shfl_xor(s[mf][r], xb);
        __syncthreads();
        float* cs = (float*)lds;
        if (wn == 0 && lane16 == 0) {
            #pragma unroll
            for (int mf = 0; mf < 3; ++mf)
                #pragma unroll
                for (int r = 0; r < 4; ++r)
                    cs[wm * 48 + mf * 16 + quad * 4 + r] = s[mf][r];
        }
        __syncthreads();
        if (wn == 1 && lane16 == 0) {
            float* pvp = (float*)outp + (size_t)gimg * NPIX + (size_t)h * HW;
            #pragma unroll
            for (int mf = 0; mf < 3; ++mf)
                #pragma unroll
                for (int r = 0; r < 4; ++r) {
                    const int px = wm * 48 + mf * 16 + quad * 4 + r;
                    pvp[px] = cs[px] + s[mf][r];
                }
        }
    }
}

// ---------- mean over 5 views + b3 ----------
__global__ __launch_bounds__(256)
void k_cost_sum(const float* __restrict__ pv, const float* __restrict__ b3, float* __restrict__ ca)
{
    const int id = blockIdx.x * 256 + threadIdx.x;
    if (id >= BBATCH * NPIX) return;
    const int b = id / NPIX, hw = id % NPIX;
    float s = 0.f;
    #pragma unroll
    for (int n = 0; n < NVIEW; ++n) s += pv[(size_t)(b * NVIEW + n) * NPIX + hw];
    ca[id] = b3[0] + 0.2f * s;
}

// ---------- collapsed 3D stage 1: 1->32ch 3x3 ----------
__global__ __launch_bounds__(256)
void k_d1(const float* __restrict__ cost_agg, const float* __restrict__ s1t,
          const float* __restrict__ rb1, float* __restrict__ t1)
{
    const int id = blockIdx.x * 256 + threadIdx.x;   // [b][hw][o], o<32
    const int o = id & 31; const int r = id >> 5;
    const int hw = r % NPIX; const int bimg = r / NPIX;
    const int y = hw / HW, x = hw % HW;
    const float* ca = cost_agg + (size_t)bimg * NPIX;
    float s = rb1[o];
    #pragma unroll
    for (int t = 0; t < 9; ++t) {
        const int yy = y + t / 3 - 1, xx = x + t % 3 - 1;
        if ((unsigned)yy < HW && (unsigned)xx < HW)
            s += s1t[t * 32 + o] * ca[yy * HW + xx];
    }
    t1[id] = fmaxf(s, 0.f);
}

// ---------- collapsed 3D stage 2: 32->16ch 3x3 ----------
__global__ __launch_bounds__(256)
void k_d2(const float* __restrict__ t1, const float* __restrict__ s2t,
          const float* __restrict__ rb2, float* __restrict__ t2)
{
    const int id = blockIdx.x * 256 + threadIdx.x;   // [b][hw][o], o<16
    const int o = id & 15; const int r = id >> 4;
    const int hw = r % NPIX; const int bimg = r / NPIX;
    const int y = hw / HW, x = hw % HW;
    float s = rb2[o];
    for (int t = 0; t < 9; ++t) {
        const int yy = y + t / 3 - 1, xx = x + t % 3 - 1;
        if ((unsigned)yy < HW && (unsigned)xx < HW) {
            const float* tp = t1 + ((size_t)bimg * NPIX + yy * HW + xx) * 32;
            #pragma unroll
            for (int i = 0; i < 32; ++i)
                s += s2t[(t * 32 + i) * 16 + o] * tp[i];
        }
    }
    t2[id] = fmaxf(s, 0.f);
}

// ---------- 1x1 16->64 + softmax + both outputs (f32) ----------
__global__ __launch_bounds__(256)
void k_d3(const float* __restrict__ t2, const float* __restrict__ r3t,
          const float* __restrict__ rb3, float* __restrict__ out)
{
    const int wv = threadIdx.x >> 6, o = threadIdx.x & 63;
    const int pix = blockIdx.x * 4 + wv;     // [b][hw]
    const float* tp = t2 + (size_t)pix * 16;
    float cv = rb3[o];
    #pragma unroll
    for (int i = 0; i < 16; ++i) cv += r3t[i * 64 + o] * tp[i];
    const float z = -cv;
    float m = z;
    #pragma unroll
    for (int off = 32; off; off >>= 1) m = fmaxf(m, __shfl_xor(m, off));
    const float e = __expf(z - m);
    float s = e;
    #pragma unroll
    for (int off = 32; off; off >>= 1) s += __shfl_xor(s, off);
    const float p = e / s;
    const size_t idx = (size_t)pix * 64 + o;
    out[idx] = cv;
    out[idx + (size_t)BBATCH * NPIX * 64] = p;
}

extern "C" void kernel_launch(void* const* d_in, const int* in_sizes, int n_in,
                              void* d_out, int out_size, void* d_ws, size_t ws_size,
                              hipStream_t stream)
{
    (void)in_sizes; (void)n_in; (void)out_size;
    const float* focal = (const float*)d_in[0];
    const float* W1  = (const float*)d_in[3];
    const float* b1  = (const float*)d_in[4];
    const float* W2  = (const float*)d_in[5];
    const float* b2  = (const float*)d_in[6];
    const float* W3  = (const float*)d_in[7];
    const float* b3  = (const float*)d_in[8];
    const float* R1  = (const float*)d_in[9];
    const float* rb1 = (const float*)d_in[10];
    const float* R2  = (const float*)d_in[11];
    const float* rb2 = (const float*)d_in[12];
    const float* R3  = (const float*)d_in[13];
    const float* rb3 = (const float*)d_in[14];

    char* ws = (char*)d_ws;
    size_t off = 0;
    auto alloc = [&](size_t sz) { char* p = ws + off; off = (off + sz + 255) & ~(size_t)255; return p; };
    const size_t IMG = (size_t)HW * 8 * HW * 32 * 2;       // 4,718,592 B (blocked f16 img)
    u16*   w1a  = (u16*)  alloc(1179648);
    u16*   w1b  = (u16*)  alloc(1179648);
    u16*   w2t  = (u16*)  alloc(589824);
    float* s1t  = (float*)alloc(1152);
    float* s2t  = (float*)alloc(18432);
    float* r3t  = (float*)alloc(4096);
    float* ca   = (float*)alloc(73728);
    float* t1   = (float*)alloc(2359296);
    float* t2   = (float*)alloc(1179648);
    float* pv   = (float*)alloc(NIMG * NPIX * 4);          // 368,640
    u16*   refp   = (u16*)alloc(BBATCH * IMG);             // 9,437,184
    u16*   feats2 = (u16*)alloc(BBATCH * IMG);             // 9,437,184
    const size_t base = off;                               // ~25.9 MB
    int C = 1;
    if (base + 20 * IMG + 512 <= ws_size)      C = 10;
    else if (base + 10 * IMG + 512 <= ws_size) C = 5;
    else if (base + 4 * IMG + 512 <= ws_size)  C = 2;
    u16* feats = (u16*)alloc((size_t)C * IMG);
    u16* x1    = (u16*)alloc((size_t)C * IMG);

    k_prep_w<<<(890656 + 255) / 256, 256, 0, stream>>>(W1, W2, R1, R2, R3, w1a, w1b, w2t, s1t, s2t, r3t);

    // transpose the two reference images (n=0 of each batch) and run the ref half of conv1
    k_tr<<<dim3(8, HW, BBATCH), 256, 0, stream>>>(focal, feats2, 0, NVIEW);
    k_conv<0><<<dim3(HW, BBATCH, 2), 256, 0, stream>>>(feats2, w1b, nullptr, nullptr, nullptr, refp, 0);

    for (int ib = 0; ib < NIMG; ib += C) {
        k_tr<<<dim3(8, HW, C), 256, 0, stream>>>(focal, feats, ib, 1);
        k_conv<1><<<dim3(HW, C, 2), 256, 0, stream>>>(feats, w1a, refp, b1, nullptr, x1, ib);
        k_conv<2><<<dim3(HW, C, 1), 256, 0, stream>>>(x1, w2t, nullptr, b2, W3, pv, ib);
    }

    k_cost_sum<<<(BBATCH * NPIX + 255) / 256, 256, 0, stream>>>(pv, b3, ca);
    k_d1<<<(BBATCH * NPIX * 32) / 256, 256, 0, stream>>>(ca, s1t, rb1, t1);
    k_d2<<<(BBATCH * NPIX * 16) / 256, 256, 0, stream>>>(t1, s2t, rb2, t2);
    k_d3<<<(BBATCH * NPIX) / 4, 256, 0, stream>>>(t2, r3t, rb3, (float*)d_out);
}